// Round 1
// baseline (791.795 us; speedup 1.0000x reference)
//
#include <hip/hip_runtime.h>
#include <cstdint>

#define BB 16
#define NN 5000
#define FIN 32
#define DDF 64
#define JALL 320            // 64 critic + 128 alpha + 128 beta
#define NB1 512             // blocks for layer-1 MLP streaming
#define KROWS 320000        // N*D
#define CHUNK1 (KROWS/NB1)  // 625

// ---------- special functions (f32, accurate ~1e-6 for x>1) ----------
__device__ __forceinline__ float softplusf_(float z){
  return z > 20.f ? z : log1pf(expf(z));
}
__device__ float gammalnf_(float x){
  float acc = 0.f;
  while (x < 8.f){ acc -= logf(x); x += 1.f; }
  float ix = 1.f/x, ix2 = ix*ix;
  return acc + (x-0.5f)*logf(x) - x + 0.91893853320467274f
       + ix*(8.3333333333333333e-2f + ix2*(-2.7777777777777778e-3f
       + ix2*(7.9365079365079365e-4f + ix2*(-5.9523809523809524e-4f))));
}
__device__ float digammaf_(float x){
  float acc = 0.f;
  while (x < 6.f){ acc -= 1.f/x; x += 1.f; }
  float ix = 1.f/x, ix2 = ix*ix;
  return acc + logf(x) - 0.5f*ix
       - ix2*(8.3333333333333333e-2f - ix2*(8.3333333333333333e-3f - ix2*3.968253968253968e-3f));
}

// ---------- CSR build ----------
__global__ void k_count(const int* __restrict__ ei, int* __restrict__ deg, int E){
  int e = blockIdx.x*256 + threadIdx.x;
  if (e < E) atomicAdd(&deg[ei[E+e]], 1);
}

__global__ __launch_bounds__(1024) void k_scan(const int* __restrict__ deg, int* __restrict__ offs,
                                               int* __restrict__ cursor, float* __restrict__ dinv){
  __shared__ int s[1024];
  int t = threadIdx.x;
  int v[5]; int sum = 0;
  int base = t*5;
  #pragma unroll
  for (int i=0;i<5;i++){ int idx=base+i; v[i] = (idx<NN) ? deg[idx] : 0; sum += v[i]; }
  s[t] = sum;
  __syncthreads();
  for (int off=1; off<1024; off<<=1){
    int add = (t>=off) ? s[t-off] : 0;
    __syncthreads();
    s[t] += add;
    __syncthreads();
  }
  int run = s[t] - sum;  // exclusive prefix of this chunk
  #pragma unroll
  for (int i=0;i<5;i++){
    int idx = base+i;
    if (idx < NN){
      offs[idx] = run; cursor[idx] = run;
      dinv[idx] = rsqrtf((float)(v[i]+1));   // +1 self-loop
      run += v[i];
    }
  }
  if (t==1023) offs[NN] = s[1023];
}

__global__ void k_fill(const int* __restrict__ ei, int* __restrict__ cursor,
                       int* __restrict__ csr, int E){
  int e = blockIdx.x*256 + threadIdx.x;
  if (e < E){
    int d = ei[E+e];
    int pos = atomicAdd(&cursor[d], 1);
    csr[pos] = ei[e];
  }
}

// ---------- GCN dense parts: ht[n][d][b] = dinv[n] * (in@W)[n][d][b] ----------
__global__ __launch_bounds__(256) void k_gemm1(const float* __restrict__ x, const float* __restrict__ W1,
                                               const float* __restrict__ dinv, float* __restrict__ ht){
  __shared__ float W1s[FIN*DDF];                    // 8 KB
  __shared__ alignas(16) float xs[4][FIN][20];      // pad 20: f4-aligned, conflict-free reads
  int t = threadIdx.x;
  int node0 = blockIdx.x*4;
  for (int i=t;i<FIN*DDF;i+=256) W1s[i] = W1[i];
  for (int i=t;i<4*16*FIN;i+=256){
    int ln = i>>9, rem = i&511, b = rem>>5, k = rem&31;
    xs[ln][k][b] = x[((size_t)b*NN + node0+ln)*FIN + k];
  }
  __syncthreads();
  int ln = t>>6, l = t&63;
  int d0 = (l&15)*4, b0 = (l>>4)*4;
  float acc[4][4] = {};
  for (int k=0;k<FIN;k++){
    const float4 wv = *(const float4*)&W1s[k*DDF + d0];
    const float4 xv = *(const float4*)&xs[ln][k][b0];
    float w[4]={wv.x,wv.y,wv.z,wv.w}, xr[4]={xv.x,xv.y,xv.z,xv.w};
    #pragma unroll
    for (int di=0;di<4;di++)
      #pragma unroll
      for (int bi=0;bi<4;bi++)
        acc[di][bi] = fmaf(w[di], xr[bi], acc[di][bi]);
  }
  int n = node0 + ln;
  float dn = dinv[n];
  float* op = &ht[(size_t)n*1024];
  #pragma unroll
  for (int di=0;di<4;di++){
    float4 o; o.x=acc[di][0]*dn; o.y=acc[di][1]*dn; o.z=acc[di][2]*dn; o.w=acc[di][3]*dn;
    *(float4*)&op[(d0+di)*16 + b0] = o;
  }
}

__global__ __launch_bounds__(256) void k_gemm2(const float* __restrict__ h1, const float* __restrict__ W2,
                                               const float* __restrict__ dinv, float* __restrict__ ht){
  __shared__ float W2s[DDF*DDF];        // 16 KB
  __shared__ float hs[4*1024];          // 16 KB, layout [node][k][b] (direct copy)
  int t = threadIdx.x;
  int node0 = blockIdx.x*4;
  for (int i=t;i<DDF*DDF;i+=256) W2s[i] = W2[i];
  const float4* src = (const float4*)&h1[(size_t)node0*1024];
  float4* dst4 = (float4*)hs;
  for (int i=t;i<1024;i+=256) dst4[i] = src[i];
  __syncthreads();
  int ln = t>>6, l = t&63;
  int d0 = (l&15)*4, b0 = (l>>4)*4;
  float acc[4][4] = {};
  for (int k=0;k<DDF;k++){
    const float4 wv = *(const float4*)&W2s[k*DDF + d0];
    const float4 xv = *(const float4*)&hs[ln*1024 + k*16 + b0];
    float w[4]={wv.x,wv.y,wv.z,wv.w}, xr[4]={xv.x,xv.y,xv.z,xv.w};
    #pragma unroll
    for (int di=0;di<4;di++)
      #pragma unroll
      for (int bi=0;bi<4;bi++)
        acc[di][bi] = fmaf(w[di], xr[bi], acc[di][bi]);
  }
  int n = node0 + ln;
  float dn = dinv[n];
  float* op = &ht[(size_t)n*1024];
  #pragma unroll
  for (int di=0;di<4;di++){
    float4 o; o.x=acc[di][0]*dn; o.y=acc[di][1]*dn; o.z=acc[di][2]*dn; o.w=acc[di][3]*dn;
    *(float4*)&op[(d0+di)*16 + b0] = o;
  }
}

// ---------- aggregation: out[n] = tanh(dinv[n]*(ht[n] + sum ht[src]) + bias[d]) ----------
__global__ __launch_bounds__(256) void k_agg(const float* __restrict__ ht, const int* __restrict__ csr,
                                             const int* __restrict__ offs, const float* __restrict__ dinv,
                                             const float* __restrict__ bias, float* __restrict__ out){
  int n = blockIdx.x, t = threadIdx.x;
  __shared__ int es[256];
  int beg = offs[n], end = offs[n+1];
  const float4 self = *(const float4*)&ht[(size_t)n*1024 + t*4];
  float ax = self.x, ay = self.y, az = self.z, aw = self.w;
  for (int base=beg; base<end; base+=256){
    int cnt = min(256, end-base);
    __syncthreads();
    if (t < cnt) es[t] = csr[base+t];
    __syncthreads();
    for (int j=0;j<cnt;j++){
      const float4 v = *(const float4*)&ht[(size_t)es[j]*1024 + t*4];
      ax+=v.x; ay+=v.y; az+=v.z; aw+=v.w;
    }
  }
  float dn = dinv[n];
  float bb = bias[t>>2];     // inner = t*4 = d*16+b -> d = t>>2
  float4 o;
  o.x = tanhf(fmaf(dn, ax, bb));
  o.y = tanhf(fmaf(dn, ay, bb));
  o.z = tanhf(fmaf(dn, az, bb));
  o.w = tanhf(fmaf(dn, aw, bb));
  *(float4*)&out[(size_t)n*1024 + t*4] = o;
}

// ---------- MLP layer 1: stream W once, obs_t[r][b] broadcast, 4b x 4j tile ----------
template<int J>
__global__ __launch_bounds__(256) void k_mlp1(const float* __restrict__ W, const float* __restrict__ obs,
                                              float* __restrict__ partial, int colOff){
  constexpr int JQ = J/4;
  constexpr int TPR = JQ*4;       // threads covering one row (all 16 b x J)
  constexpr int RPI = 256/TPR;    // row streams per block iteration
  int t = threadIdx.x;
  int jq = t % JQ;
  int bq = (t / JQ) & 3;
  int rh = t / TPR;
  int j0 = jq*4, b0 = bq*4;
  int r0 = blockIdx.x*CHUNK1, r1 = r0 + CHUNK1;
  float acc[4][4] = {};
  #pragma unroll 2
  for (int r = r0 + rh; r < r1; r += RPI){
    const float4 wv = *(const float4*)&W[(size_t)r*J + j0];
    const float4 ov = *(const float4*)&obs[(size_t)r*16 + b0];
    float w[4]={wv.x,wv.y,wv.z,wv.w}, o[4]={ov.x,ov.y,ov.z,ov.w};
    #pragma unroll
    for (int bi=0;bi<4;bi++)
      #pragma unroll
      for (int ji=0;ji<4;ji++)
        acc[bi][ji] = fmaf(o[bi], w[ji], acc[bi][ji]);
  }
  __shared__ float red[256][17];  // +1 pad breaks 16-stride bank aliasing
  #pragma unroll
  for (int bi=0;bi<4;bi++)
    #pragma unroll
    for (int ji=0;ji<4;ji++)
      red[t][bi*4+ji] = acc[bi][ji];
  __syncthreads();
  if (rh == 0){
    #pragma unroll
    for (int s=1;s<RPI;s++)
      #pragma unroll
      for (int i=0;i<16;i++)
        acc[i>>2][i&3] += red[t + s*TPR][i];
    float* dst = partial + (size_t)blockIdx.x*(BB*JALL);
    #pragma unroll
    for (int bi=0;bi<4;bi++)
      #pragma unroll
      for (int ji=0;ji<4;ji++)
        dst[(b0+bi)*JALL + colOff + j0 + ji] = acc[bi][ji];
  }
}

// ---------- reduce partials + bias + tanh -> act1[b][320] ----------
__global__ void k_red(const float* __restrict__ partial, const float* __restrict__ bc1,
                      const float* __restrict__ ba1, const float* __restrict__ bb1,
                      float* __restrict__ act1){
  int o = blockIdx.x*256 + threadIdx.x;   // 0..5119
  float s0=0.f, s1=0.f, s2=0.f, s3=0.f;
  for (int i=0;i<NB1;i+=4){
    s0 += partial[(size_t)(i+0)*(BB*JALL) + o];
    s1 += partial[(size_t)(i+1)*(BB*JALL) + o];
    s2 += partial[(size_t)(i+2)*(BB*JALL) + o];
    s3 += partial[(size_t)(i+3)*(BB*JALL) + o];
  }
  float s = (s0+s1)+(s2+s3);
  int col = o % JALL;
  float bias = col < 64 ? bc1[col] : (col < 192 ? ba1[col-64] : bb1[col-192]);
  act1[o] = tanhf(s + bias);
}

// ---------- tails: critic full, actor hidden layer 2 ----------
__global__ __launch_bounds__(256) void k_tail(const float* __restrict__ act1,
    const float* __restrict__ Wc2, const float* __restrict__ bc2,
    const float* __restrict__ Wc3, const float* __restrict__ bc3,
    const float* __restrict__ Wa2, const float* __restrict__ ba2,
    const float* __restrict__ Wb2, const float* __restrict__ bb2,
    float* __restrict__ ah2, float* __restrict__ bh2, float* __restrict__ out){
  int t = threadIdx.x;
  if (blockIdx.x == 0){
    __shared__ float c1[16][64];
    __shared__ float c2[16][64];
    for (int i=t;i<16*64;i+=256) c1[i>>6][i&63] = act1[(i>>6)*JALL + (i&63)];
    __syncthreads();
    int j = t & 63, brow = t >> 6;
    for (int i=0;i<4;i++){
      int b = brow*4 + i;
      float s = bc2[j];
      for (int k=0;k<64;k++) s = fmaf(c1[b][k], Wc2[k*64+j], s);
      c2[b][j] = tanhf(s);
    }
    __syncthreads();
    if (t < 16){
      float s = bc3[0];
      for (int k=0;k<64;k++) s = fmaf(c2[t][k], Wc3[k], s);
      out[3*BB*NN + t] = s;   // value at offset 240000
    }
  } else {
    const float* Wx2 = (blockIdx.x==1) ? Wa2 : Wb2;
    const float* bx2 = (blockIdx.x==1) ? ba2 : bb2;
    float* ox       = (blockIdx.x==1) ? ah2 : bh2;
    int cOff        = (blockIdx.x==1) ? 64 : 192;
    __shared__ float s1[16][128];
    for (int i=t;i<16*128;i+=256) s1[i>>7][i&127] = act1[(i>>7)*JALL + cOff + (i&127)];
    __syncthreads();
    int j = t & 127, bh = t >> 7;
    for (int i=0;i<8;i++){
      int b = bh*8 + i;
      float s = bx2[j];
      for (int k=0;k<128;k++) s = fmaf(s1[b][k], Wx2[k*128+j], s);
      ox[b*128 + j] = tanhf(s);
    }
  }
}

// ---------- final: actor layer 3 + Beta statistics ----------
__global__ __launch_bounds__(256) void k_final(const float* __restrict__ ah2, const float* __restrict__ bh2,
    const float* __restrict__ Wa3, const float* __restrict__ ba3,
    const float* __restrict__ Wb3, const float* __restrict__ bb3,
    float* __restrict__ out){
  __shared__ float as[128], bs[128];
  int t = threadIdx.x, b = blockIdx.y;
  if (t < 128){ as[t] = ah2[b*128+t]; bs[t] = bh2[b*128+t]; }
  __syncthreads();
  int n = blockIdx.x*256 + t;
  if (n >= NN) return;
  float sa = ba3[n], sb = bb3[n];
  #pragma unroll 4
  for (int k=0;k<128;k++){
    sa = fmaf(as[k], Wa3[k*NN+n], sa);
    sb = fmaf(bs[k], Wb3[k*NN+n], sb);
  }
  float alpha = 1.f + softplusf_(sa);
  float beta  = 1.f + softplusf_(sb);
  float action = alpha/(alpha+beta);
  float la = logf(action), lb = log1pf(-action);
  float logBt = gammalnf_(alpha) + gammalnf_(beta) - gammalnf_(alpha+beta);
  float logp = (alpha-1.f)*la + (beta-1.f)*lb - logBt;
  float ent = logBt - (alpha-1.f)*digammaf_(alpha) - (beta-1.f)*digammaf_(beta)
            + (alpha+beta-2.f)*digammaf_(alpha+beta);
  int o = b*NN + n;
  out[o]               = action;
  out[BB*NN + o]       = logp;
  out[2*BB*NN + o]     = ent;
}

extern "C" void kernel_launch(void* const* d_in, const int* in_sizes, int n_in,
                              void* d_out, int out_size, void* d_ws, size_t ws_size,
                              hipStream_t stream)
{
  const float* x   = (const float*)d_in[0];
  const int*   ei  = (const int*)d_in[1];
  const float* W1  = (const float*)d_in[2];
  const float* b1  = (const float*)d_in[3];
  const float* W2  = (const float*)d_in[4];
  const float* b2  = (const float*)d_in[5];
  const float* Wc1 = (const float*)d_in[6];
  const float* bc1 = (const float*)d_in[7];
  const float* Wc2 = (const float*)d_in[8];
  const float* bc2 = (const float*)d_in[9];
  const float* Wc3 = (const float*)d_in[10];
  const float* bc3 = (const float*)d_in[11];
  const float* Wa1 = (const float*)d_in[12];
  const float* ba1 = (const float*)d_in[13];
  const float* Wa2 = (const float*)d_in[14];
  const float* ba2 = (const float*)d_in[15];
  const float* Wa3 = (const float*)d_in[16];
  const float* ba3 = (const float*)d_in[17];
  const float* Wb1 = (const float*)d_in[18];
  const float* bb1 = (const float*)d_in[19];
  const float* Wb2 = (const float*)d_in[20];
  const float* bb2 = (const float*)d_in[21];
  const float* Wb3 = (const float*)d_in[22];
  const float* bb3 = (const float*)d_in[23];
  float* out = (float*)d_out;
  const int E = in_sizes[1]/2;

  char* p = (char*)d_ws;
  auto carve = [&](size_t bytes)->char*{ char* r = p; p += (bytes + 255) & ~(size_t)255; return r; };
  int*   deg     = (int*)carve((size_t)NN*4);
  int*   offs    = (int*)carve((size_t)(NN+1)*4);
  int*   cursor  = (int*)carve((size_t)NN*4);
  float* dinv    = (float*)carve((size_t)NN*4);
  int*   csr     = (int*)carve((size_t)E*4);
  float* partial = (float*)carve((size_t)NB1*BB*JALL*4);
  float* act1    = (float*)carve((size_t)BB*JALL*4);
  float* ah2     = (float*)carve((size_t)BB*128*4);
  float* bh2     = (float*)carve((size_t)BB*128*4);
  float* bufA    = (float*)carve((size_t)NN*1024*4);   // ht (pre-agg, dinv-scaled)
  float* bufB    = (float*)carve((size_t)NN*1024*4);   // h1, then obs_t

  hipMemsetAsync(deg, 0, (size_t)NN*4, stream);
  k_count<<<(E+255)/256, 256, 0, stream>>>(ei, deg, E);
  k_scan<<<1, 1024, 0, stream>>>(deg, offs, cursor, dinv);
  k_fill<<<(E+255)/256, 256, 0, stream>>>(ei, cursor, csr, E);

  k_gemm1<<<NN/4, 256, 0, stream>>>(x, W1, dinv, bufA);
  k_agg<<<NN, 256, 0, stream>>>(bufA, csr, offs, dinv, b1, bufB);
  k_gemm2<<<NN/4, 256, 0, stream>>>(bufB, W2, dinv, bufA);
  k_agg<<<NN, 256, 0, stream>>>(bufA, csr, offs, dinv, b2, bufB);   // bufB = obs_t[r][b]

  k_mlp1<64> <<<NB1, 256, 0, stream>>>(Wc1, bufB, partial, 0);
  k_mlp1<128><<<NB1, 256, 0, stream>>>(Wa1, bufB, partial, 64);
  k_mlp1<128><<<NB1, 256, 0, stream>>>(Wb1, bufB, partial, 192);
  k_red<<<(BB*JALL)/256, 256, 0, stream>>>(partial, bc1, ba1, bb1, act1);

  k_tail<<<3, 256, 0, stream>>>(act1, Wc2, bc2, Wc3, bc3, Wa2, ba2, Wb2, bb2, ah2, bh2, out);
  k_final<<<dim3(20, BB), 256, 0, stream>>>(ah2, bh2, Wa3, ba3, Wb3, bb3, out);
}

// Round 2
// 666.734 us; speedup vs baseline: 1.1876x; 1.1876x over previous
//
#include <hip/hip_runtime.h>
#include <cstdint>

#define BB 16
#define NN 5000
#define FIN 32
#define DDF 64
#define JALL 320            // 64 critic + 128 alpha + 128 beta
#define KROWS 320000        // N*D
#define NCH 250             // K-chunks for layer-1 MLP
#define CHROWS 1280         // rows per chunk (= KROWS/NCH)
#define SUBR 256            // rows per LDS staging sub-chunk

// ---------- special functions (f32, accurate ~1e-6 for x>1) ----------
__device__ __forceinline__ float softplusf_(float z){
  return z > 20.f ? z : log1pf(expf(z));
}
__device__ float gammalnf_(float x){
  float acc = 0.f;
  while (x < 8.f){ acc -= logf(x); x += 1.f; }
  float ix = 1.f/x, ix2 = ix*ix;
  return acc + (x-0.5f)*logf(x) - x + 0.91893853320467274f
       + ix*(8.3333333333333333e-2f + ix2*(-2.7777777777777778e-3f
       + ix2*(7.9365079365079365e-4f + ix2*(-5.9523809523809524e-4f))));
}
__device__ float digammaf_(float x){
  float acc = 0.f;
  while (x < 6.f){ acc -= 1.f/x; x += 1.f; }
  float ix = 1.f/x, ix2 = ix*ix;
  return acc + logf(x) - 0.5f*ix
       - ix2*(8.3333333333333333e-2f - ix2*(8.3333333333333333e-3f - ix2*3.968253968253968e-3f));
}

// ---------- CSR build ----------
__global__ void k_count(const int* __restrict__ ei, int* __restrict__ deg, int E){
  int e = blockIdx.x*256 + threadIdx.x;
  if (e < E) atomicAdd(&deg[ei[E+e]], 1);
}

__global__ __launch_bounds__(1024) void k_scan(const int* __restrict__ deg, int* __restrict__ offs,
                                               int* __restrict__ cursor, float* __restrict__ dinv){
  __shared__ int s[1024];
  int t = threadIdx.x;
  int v[5]; int sum = 0;
  int base = t*5;
  #pragma unroll
  for (int i=0;i<5;i++){ int idx=base+i; v[i] = (idx<NN) ? deg[idx] : 0; sum += v[i]; }
  s[t] = sum;
  __syncthreads();
  for (int off=1; off<1024; off<<=1){
    int add = (t>=off) ? s[t-off] : 0;
    __syncthreads();
    s[t] += add;
    __syncthreads();
  }
  int run = s[t] - sum;  // exclusive prefix of this chunk
  #pragma unroll
  for (int i=0;i<5;i++){
    int idx = base+i;
    if (idx < NN){
      offs[idx] = run; cursor[idx] = run;
      dinv[idx] = rsqrtf((float)(v[i]+1));   // +1 self-loop
      run += v[i];
    }
  }
  if (t==1023) offs[NN] = s[1023];
}

__global__ void k_fill(const int* __restrict__ ei, int* __restrict__ cursor,
                       int* __restrict__ csr, int E){
  int e = blockIdx.x*256 + threadIdx.x;
  if (e < E){
    int d = ei[E+e];
    int pos = atomicAdd(&cursor[d], 1);
    csr[pos] = ei[e];
  }
}

// ---------- GCN dense parts: ht[n][d][b] = dinv[n] * (in@W)[n][d][b] ----------
__global__ __launch_bounds__(256) void k_gemm1(const float* __restrict__ x, const float* __restrict__ W1,
                                               const float* __restrict__ dinv, float* __restrict__ ht){
  __shared__ float W1s[FIN*DDF];                    // 8 KB
  __shared__ alignas(16) float xs[4][FIN][20];      // pad 20: f4-aligned, conflict-free reads
  int t = threadIdx.x;
  int node0 = blockIdx.x*4;
  for (int i=t;i<FIN*DDF;i+=256) W1s[i] = W1[i];
  for (int i=t;i<4*16*FIN;i+=256){
    int ln = i>>9, rem = i&511, b = rem>>5, k = rem&31;
    xs[ln][k][b] = x[((size_t)b*NN + node0+ln)*FIN + k];
  }
  __syncthreads();
  int ln = t>>6, l = t&63;
  int d0 = (l&15)*4, b0 = (l>>4)*4;
  float acc[4][4] = {};
  for (int k=0;k<FIN;k++){
    const float4 wv = *(const float4*)&W1s[k*DDF + d0];
    const float4 xv = *(const float4*)&xs[ln][k][b0];
    float w[4]={wv.x,wv.y,wv.z,wv.w}, xr[4]={xv.x,xv.y,xv.z,xv.w};
    #pragma unroll
    for (int di=0;di<4;di++)
      #pragma unroll
      for (int bi=0;bi<4;bi++)
        acc[di][bi] = fmaf(w[di], xr[bi], acc[di][bi]);
  }
  int n = node0 + ln;
  float dn = dinv[n];
  float* op = &ht[(size_t)n*1024];
  #pragma unroll
  for (int di=0;di<4;di++){
    float4 o; o.x=acc[di][0]*dn; o.y=acc[di][1]*dn; o.z=acc[di][2]*dn; o.w=acc[di][3]*dn;
    *(float4*)&op[(d0+di)*16 + b0] = o;
  }
}

__global__ __launch_bounds__(256) void k_gemm2(const float* __restrict__ h1, const float* __restrict__ W2,
                                               const float* __restrict__ dinv, float* __restrict__ ht){
  __shared__ float W2s[DDF*DDF];        // 16 KB
  __shared__ float hs[4*1024];          // 16 KB, layout [node][k][b] (direct copy)
  int t = threadIdx.x;
  int node0 = blockIdx.x*4;
  for (int i=t;i<DDF*DDF;i+=256) W2s[i] = W2[i];
  const float4* src = (const float4*)&h1[(size_t)node0*1024];
  float4* dst4 = (float4*)hs;
  for (int i=t;i<1024;i+=256) dst4[i] = src[i];
  __syncthreads();
  int ln = t>>6, l = t&63;
  int d0 = (l&15)*4, b0 = (l>>4)*4;
  float acc[4][4] = {};
  for (int k=0;k<DDF;k++){
    const float4 wv = *(const float4*)&W2s[k*DDF + d0];
    const float4 xv = *(const float4*)&hs[ln*1024 + k*16 + b0];
    float w[4]={wv.x,wv.y,wv.z,wv.w}, xr[4]={xv.x,xv.y,xv.z,xv.w};
    #pragma unroll
    for (int di=0;di<4;di++)
      #pragma unroll
      for (int bi=0;bi<4;bi++)
        acc[di][bi] = fmaf(w[di], xr[bi], acc[di][bi]);
  }
  int n = node0 + ln;
  float dn = dinv[n];
  float* op = &ht[(size_t)n*1024];
  #pragma unroll
  for (int di=0;di<4;di++){
    float4 o; o.x=acc[di][0]*dn; o.y=acc[di][1]*dn; o.z=acc[di][2]*dn; o.w=acc[di][3]*dn;
    *(float4*)&op[(d0+di)*16 + b0] = o;
  }
}

// ---------- aggregation: out[n] = tanh(dinv[n]*(ht[n] + sum ht[src]) + bias[d]) ----------
__global__ __launch_bounds__(256) void k_agg(const float* __restrict__ ht, const int* __restrict__ csr,
                                             const int* __restrict__ offs, const float* __restrict__ dinv,
                                             const float* __restrict__ bias, float* __restrict__ out){
  int n = blockIdx.x, t = threadIdx.x;
  __shared__ int es[256];
  int beg = offs[n], end = offs[n+1];
  const float4 self = *(const float4*)&ht[(size_t)n*1024 + t*4];
  float ax = self.x, ay = self.y, az = self.z, aw = self.w;
  for (int base=beg; base<end; base+=256){
    int cnt = min(256, end-base);
    __syncthreads();
    if (t < cnt) es[t] = csr[base+t];
    __syncthreads();
    for (int j=0;j<cnt;j++){
      const float4 v = *(const float4*)&ht[(size_t)es[j]*1024 + t*4];
      ax+=v.x; ay+=v.y; az+=v.z; aw+=v.w;
    }
  }
  float dn = dinv[n];
  float bb = bias[t>>2];     // inner = t*4 = d*16+b -> d = t>>2
  float4 o;
  o.x = tanhf(fmaf(dn, ax, bb));
  o.y = tanhf(fmaf(dn, ay, bb));
  o.z = tanhf(fmaf(dn, az, bb));
  o.w = tanhf(fmaf(dn, aw, bb));
  *(float4*)&out[(size_t)n*1024 + t*4] = o;
}

// ---------- fused MLP layer 1 ----------
// C[16 b x 320 j] = obs_t[K x 16]^T @ [Wc1 | Wa1 | Wb1]. Streams W exactly once,
// coalesced float4 per lane; obs chunk staged in LDS (pad-20 rows: the 4 row-addrs
// per wave-read land on distinct bank quads). 16b x 4j register tile: 64 FMA per
// 16 B of W -> memory-bound by construction.
#define FMA4(a,s,w) { a.x=fmaf(s,w.x,a.x); a.y=fmaf(s,w.y,a.y); a.z=fmaf(s,w.z,a.z); a.w=fmaf(s,w.w,a.w); }
__global__ __launch_bounds__(256) void k_mlp1f(const float* __restrict__ Wc1,
    const float* __restrict__ Wa1, const float* __restrict__ Wb1,
    const float* __restrict__ obs, float* __restrict__ partial){
  __shared__ float smem[SUBR*20];   // 20 KB obs stage; reused as reduction buffer
  int t = threadIdx.x;
  int tile = blockIdx.y;
  const float* W; int sj, jb, cb;
  if      (tile==0){ W=Wc1; sj=64;  jb=0;  cb=0;   }
  else if (tile==1){ W=Wa1; sj=128; jb=0;  cb=64;  }
  else if (tile==2){ W=Wa1; sj=128; jb=64; cb=128; }
  else if (tile==3){ W=Wb1; sj=128; jb=0;  cb=192; }
  else             { W=Wb1; sj=128; jb=64; cb=256; }
  int jq = t & 15, rg = t >> 4;
  const float* Wp = W + jb + jq*4;
  int chunk0 = blockIdx.x * CHROWS;
  float4 acc[16];
  #pragma unroll
  for (int b=0;b<16;b++) acc[b] = make_float4(0.f,0.f,0.f,0.f);

  for (int sub=0; sub<CHROWS/SUBR; sub++){
    int rbase = chunk0 + sub*SUBR;
    __syncthreads();
    #pragma unroll
    for (int p=0;p<4;p++){
      int idx = t + p*256;                 // 0..1023 float4s
      int row = idx>>2, c = idx&3;
      float4 v = *(const float4*)&obs[(size_t)(rbase+row)*16 + c*4];
      *(float4*)&smem[row*20 + c*4] = v;
    }
    __syncthreads();
    #pragma unroll 4
    for (int i=0;i<16;i++){
      int r = i*16 + rg;
      float4 w = *(const float4*)&Wp[(size_t)(rbase + r)*sj];
      const float* ob = &smem[r*20];
      float4 o0 = *(const float4*)&ob[0];
      float4 o1 = *(const float4*)&ob[4];
      float4 o2 = *(const float4*)&ob[8];
      float4 o3 = *(const float4*)&ob[12];
      FMA4(acc[ 0], o0.x, w); FMA4(acc[ 1], o0.y, w); FMA4(acc[ 2], o0.z, w); FMA4(acc[ 3], o0.w, w);
      FMA4(acc[ 4], o1.x, w); FMA4(acc[ 5], o1.y, w); FMA4(acc[ 6], o1.z, w); FMA4(acc[ 7], o1.w, w);
      FMA4(acc[ 8], o2.x, w); FMA4(acc[ 9], o2.y, w); FMA4(acc[10], o2.z, w); FMA4(acc[11], o2.w, w);
      FMA4(acc[12], o3.x, w); FMA4(acc[13], o3.y, w); FMA4(acc[14], o3.z, w); FMA4(acc[15], o3.w, w);
    }
  }

  // butterfly-reduce the 4 rowgroups within each wave (lanes differ by 16, 32)
  #pragma unroll
  for (int b=0;b<16;b++){
    float4 a = acc[b];
    a.x += __shfl_xor(a.x,16); a.y += __shfl_xor(a.y,16); a.z += __shfl_xor(a.z,16); a.w += __shfl_xor(a.w,16);
    a.x += __shfl_xor(a.x,32); a.y += __shfl_xor(a.y,32); a.z += __shfl_xor(a.z,32); a.w += __shfl_xor(a.w,32);
    acc[b] = a;
  }
  __syncthreads();                          // all obs reads done -> reuse smem
  int wv = t>>6, lane = t&63;
  if (lane < 16){
    #pragma unroll
    for (int b=0;b<16;b++)
      *(float4*)&smem[wv*1024 + lane*64 + b*4] = acc[b];
  }
  __syncthreads();
  // thread t -> (b = t&15, jquad = t>>4), sums the 4 waves, writes float4
  float4 s = make_float4(0.f,0.f,0.f,0.f);
  #pragma unroll
  for (int w2=0;w2<4;w2++){
    float4 v = *(const float4*)&smem[w2*1024 + t*4];
    s.x+=v.x; s.y+=v.y; s.z+=v.z; s.w+=v.w;
  }
  float* dst = partial + (size_t)blockIdx.x*(BB*JALL) + (t&15)*JALL + cb + (t>>4)*4;
  *(float4*)dst = s;
}

// ---------- reduce partials + bias + tanh -> act1[b][320] ----------
__global__ void k_red(const float* __restrict__ partial, const float* __restrict__ bc1,
                      const float* __restrict__ ba1, const float* __restrict__ bb1,
                      float* __restrict__ act1){
  int o = blockIdx.x*256 + threadIdx.x;   // 0..5119
  float s0=0.f, s1=0.f;
  for (int i=0;i<NCH;i+=2){
    s0 += partial[(size_t)(i+0)*(BB*JALL) + o];
    s1 += partial[(size_t)(i+1)*(BB*JALL) + o];
  }
  float s = s0+s1;
  int col = o % JALL;
  float bias = col < 64 ? bc1[col] : (col < 192 ? ba1[col-64] : bb1[col-192]);
  act1[o] = tanhf(s + bias);
}

// ---------- tails: critic full, actor hidden layer 2 ----------
__global__ __launch_bounds__(256) void k_tail(const float* __restrict__ act1,
    const float* __restrict__ Wc2, const float* __restrict__ bc2,
    const float* __restrict__ Wc3, const float* __restrict__ bc3,
    const float* __restrict__ Wa2, const float* __restrict__ ba2,
    const float* __restrict__ Wb2, const float* __restrict__ bb2,
    float* __restrict__ ah2, float* __restrict__ bh2, float* __restrict__ out){
  int t = threadIdx.x;
  if (blockIdx.x == 0){
    __shared__ float c1[16][64];
    __shared__ float c2[16][64];
    for (int i=t;i<16*64;i+=256) c1[i>>6][i&63] = act1[(i>>6)*JALL + (i&63)];
    __syncthreads();
    int j = t & 63, brow = t >> 6;
    for (int i=0;i<4;i++){
      int b = brow*4 + i;
      float s = bc2[j];
      for (int k=0;k<64;k++) s = fmaf(c1[b][k], Wc2[k*64+j], s);
      c2[b][j] = tanhf(s);
    }
    __syncthreads();
    if (t < 16){
      float s = bc3[0];
      for (int k=0;k<64;k++) s = fmaf(c2[t][k], Wc3[k], s);
      out[3*BB*NN + t] = s;   // value at offset 240000
    }
  } else {
    const float* Wx2 = (blockIdx.x==1) ? Wa2 : Wb2;
    const float* bx2 = (blockIdx.x==1) ? ba2 : bb2;
    float* ox       = (blockIdx.x==1) ? ah2 : bh2;
    int cOff        = (blockIdx.x==1) ? 64 : 192;
    __shared__ float s1[16][128];
    for (int i=t;i<16*128;i+=256) s1[i>>7][i&127] = act1[(i>>7)*JALL + cOff + (i&127)];
    __syncthreads();
    int j = t & 127, bh = t >> 7;
    for (int i=0;i<8;i++){
      int b = bh*8 + i;
      float s = bx2[j];
      for (int k=0;k<128;k++) s = fmaf(s1[b][k], Wx2[k*128+j], s);
      ox[b*128 + j] = tanhf(s);
    }
  }
}

// ---------- final: actor layer 3 + Beta statistics ----------
__global__ __launch_bounds__(256) void k_final(const float* __restrict__ ah2, const float* __restrict__ bh2,
    const float* __restrict__ Wa3, const float* __restrict__ ba3,
    const float* __restrict__ Wb3, const float* __restrict__ bb3,
    float* __restrict__ out){
  __shared__ float as[128], bs[128];
  int t = threadIdx.x, b = blockIdx.y;
  if (t < 128){ as[t] = ah2[b*128+t]; bs[t] = bh2[b*128+t]; }
  __syncthreads();
  int n = blockIdx.x*256 + t;
  if (n >= NN) return;
  float sa = ba3[n], sb = bb3[n];
  #pragma unroll 4
  for (int k=0;k<128;k++){
    sa = fmaf(as[k], Wa3[k*NN+n], sa);
    sb = fmaf(bs[k], Wb3[k*NN+n], sb);
  }
  float alpha = 1.f + softplusf_(sa);
  float beta  = 1.f + softplusf_(sb);
  float action = alpha/(alpha+beta);
  float la = logf(action), lb = log1pf(-action);
  float logBt = gammalnf_(alpha) + gammalnf_(beta) - gammalnf_(alpha+beta);
  float logp = (alpha-1.f)*la + (beta-1.f)*lb - logBt;
  float ent = logBt - (alpha-1.f)*digammaf_(alpha) - (beta-1.f)*digammaf_(beta)
            + (alpha+beta-2.f)*digammaf_(alpha+beta);
  int o = b*NN + n;
  out[o]               = action;
  out[BB*NN + o]       = logp;
  out[2*BB*NN + o]     = ent;
}

extern "C" void kernel_launch(void* const* d_in, const int* in_sizes, int n_in,
                              void* d_out, int out_size, void* d_ws, size_t ws_size,
                              hipStream_t stream)
{
  const float* x   = (const float*)d_in[0];
  const int*   ei  = (const int*)d_in[1];
  const float* W1  = (const float*)d_in[2];
  const float* b1  = (const float*)d_in[3];
  const float* W2  = (const float*)d_in[4];
  const float* b2  = (const float*)d_in[5];
  const float* Wc1 = (const float*)d_in[6];
  const float* bc1 = (const float*)d_in[7];
  const float* Wc2 = (const float*)d_in[8];
  const float* bc2 = (const float*)d_in[9];
  const float* Wc3 = (const float*)d_in[10];
  const float* bc3 = (const float*)d_in[11];
  const float* Wa1 = (const float*)d_in[12];
  const float* ba1 = (const float*)d_in[13];
  const float* Wa2 = (const float*)d_in[14];
  const float* ba2 = (const float*)d_in[15];
  const float* Wa3 = (const float*)d_in[16];
  const float* ba3 = (const float*)d_in[17];
  const float* Wb1 = (const float*)d_in[18];
  const float* bb1 = (const float*)d_in[19];
  const float* Wb2 = (const float*)d_in[20];
  const float* bb2 = (const float*)d_in[21];
  const float* Wb3 = (const float*)d_in[22];
  const float* bb3 = (const float*)d_in[23];
  float* out = (float*)d_out;
  const int E = in_sizes[1]/2;

  char* p = (char*)d_ws;
  auto carve = [&](size_t bytes)->char*{ char* r = p; p += (bytes + 255) & ~(size_t)255; return r; };
  int*   deg     = (int*)carve((size_t)NN*4);
  int*   offs    = (int*)carve((size_t)(NN+1)*4);
  int*   cursor  = (int*)carve((size_t)NN*4);
  float* dinv    = (float*)carve((size_t)NN*4);
  int*   csr     = (int*)carve((size_t)E*4);
  float* partial = (float*)carve((size_t)NCH*BB*JALL*4);
  float* act1    = (float*)carve((size_t)BB*JALL*4);
  float* ah2     = (float*)carve((size_t)BB*128*4);
  float* bh2     = (float*)carve((size_t)BB*128*4);
  float* bufA    = (float*)carve((size_t)NN*1024*4);   // ht (pre-agg, dinv-scaled)
  float* bufB    = (float*)carve((size_t)NN*1024*4);   // h1, then obs_t

  hipMemsetAsync(deg, 0, (size_t)NN*4, stream);
  k_count<<<(E+255)/256, 256, 0, stream>>>(ei, deg, E);
  k_scan<<<1, 1024, 0, stream>>>(deg, offs, cursor, dinv);
  k_fill<<<(E+255)/256, 256, 0, stream>>>(ei, cursor, csr, E);

  k_gemm1<<<NN/4, 256, 0, stream>>>(x, W1, dinv, bufA);
  k_agg<<<NN, 256, 0, stream>>>(bufA, csr, offs, dinv, b1, bufB);
  k_gemm2<<<NN/4, 256, 0, stream>>>(bufB, W2, dinv, bufA);
  k_agg<<<NN, 256, 0, stream>>>(bufA, csr, offs, dinv, b2, bufB);   // bufB = obs_t[r][b]

  k_mlp1f<<<dim3(NCH, 5), 256, 0, stream>>>(Wc1, Wa1, Wb1, bufB, partial);
  k_red<<<(BB*JALL)/256, 256, 0, stream>>>(partial, bc1, ba1, bb1, act1);

  k_tail<<<3, 256, 0, stream>>>(act1, Wc2, bc2, Wc3, bc3, Wa2, ba2, Wb2, bb2, ah2, bh2, out);
  k_final<<<dim3(20, BB), 256, 0, stream>>>(ah2, bh2, Wa3, ba3, Wb3, bb3, out);
}

// Round 3
// 629.838 us; speedup vs baseline: 1.2571x; 1.0586x over previous
//
#include <hip/hip_runtime.h>
#include <cstdint>

#define BB 16
#define NN 5000
#define FIN 32
#define DDF 64
#define JALL 320            // 64 critic + 128 alpha + 128 beta
#define KROWS 320000        // N*D
#define NCH 1000            // K-chunks for layer-1 MLP
#define CHROWS 320          // rows per chunk (= KROWS/NCH)
#define ITERS (CHROWS/16)   // 20 block iterations (16 rows each)

// ---------- special functions (f32, accurate ~1e-6 for x>1) ----------
__device__ __forceinline__ float softplusf_(float z){
  return z > 20.f ? z : log1pf(expf(z));
}
__device__ float gammalnf_(float x){
  float acc = 0.f;
  while (x < 8.f){ acc -= logf(x); x += 1.f; }
  float ix = 1.f/x, ix2 = ix*ix;
  return acc + (x-0.5f)*logf(x) - x + 0.91893853320467274f
       + ix*(8.3333333333333333e-2f + ix2*(-2.7777777777777778e-3f
       + ix2*(7.9365079365079365e-4f + ix2*(-5.9523809523809524e-4f))));
}
__device__ float digammaf_(float x){
  float acc = 0.f;
  while (x < 6.f){ acc -= 1.f/x; x += 1.f; }
  float ix = 1.f/x, ix2 = ix*ix;
  return acc + logf(x) - 0.5f*ix
       - ix2*(8.3333333333333333e-2f - ix2*(8.3333333333333333e-3f - ix2*3.968253968253968e-3f));
}

// ---------- CSR build ----------
__global__ void k_count(const int* __restrict__ ei, int* __restrict__ deg, int E){
  int e = blockIdx.x*256 + threadIdx.x;
  if (e < E) atomicAdd(&deg[ei[E+e]], 1);
}

__global__ __launch_bounds__(1024) void k_scan(const int* __restrict__ deg, int* __restrict__ offs,
                                               int* __restrict__ cursor, float* __restrict__ dinv){
  __shared__ int s[1024];
  int t = threadIdx.x;
  int v[5]; int sum = 0;
  int base = t*5;
  #pragma unroll
  for (int i=0;i<5;i++){ int idx=base+i; v[i] = (idx<NN) ? deg[idx] : 0; sum += v[i]; }
  s[t] = sum;
  __syncthreads();
  for (int off=1; off<1024; off<<=1){
    int add = (t>=off) ? s[t-off] : 0;
    __syncthreads();
    s[t] += add;
    __syncthreads();
  }
  int run = s[t] - sum;  // exclusive prefix of this chunk
  #pragma unroll
  for (int i=0;i<5;i++){
    int idx = base+i;
    if (idx < NN){
      offs[idx] = run; cursor[idx] = run;
      dinv[idx] = rsqrtf((float)(v[i]+1));   // +1 self-loop
      run += v[i];
    }
  }
  if (t==1023) offs[NN] = s[1023];
}

__global__ void k_fill(const int* __restrict__ ei, int* __restrict__ cursor,
                       int* __restrict__ csr, int E){
  int e = blockIdx.x*256 + threadIdx.x;
  if (e < E){
    int d = ei[E+e];
    int pos = atomicAdd(&cursor[d], 1);
    csr[pos] = ei[e];
  }
}

// ---------- GCN dense parts: ht[n][d][b] = dinv[n] * (in@W)[n][d][b] ----------
__global__ __launch_bounds__(256) void k_gemm1(const float* __restrict__ x, const float* __restrict__ W1,
                                               const float* __restrict__ dinv, float* __restrict__ ht){
  __shared__ float W1s[FIN*DDF];                    // 8 KB
  __shared__ alignas(16) float xs[4][FIN][20];      // pad 20: f4-aligned, conflict-free reads
  int t = threadIdx.x;
  int node0 = blockIdx.x*4;
  for (int i=t;i<FIN*DDF;i+=256) W1s[i] = W1[i];
  for (int i=t;i<4*16*FIN;i+=256){
    int ln = i>>9, rem = i&511, b = rem>>5, k = rem&31;
    xs[ln][k][b] = x[((size_t)b*NN + node0+ln)*FIN + k];
  }
  __syncthreads();
  int ln = t>>6, l = t&63;
  int d0 = (l&15)*4, b0 = (l>>4)*4;
  float acc[4][4] = {};
  for (int k=0;k<FIN;k++){
    const float4 wv = *(const float4*)&W1s[k*DDF + d0];
    const float4 xv = *(const float4*)&xs[ln][k][b0];
    float w[4]={wv.x,wv.y,wv.z,wv.w}, xr[4]={xv.x,xv.y,xv.z,xv.w};
    #pragma unroll
    for (int di=0;di<4;di++)
      #pragma unroll
      for (int bi=0;bi<4;bi++)
        acc[di][bi] = fmaf(w[di], xr[bi], acc[di][bi]);
  }
  int n = node0 + ln;
  float dn = dinv[n];
  float* op = &ht[(size_t)n*1024];
  #pragma unroll
  for (int di=0;di<4;di++){
    float4 o; o.x=acc[di][0]*dn; o.y=acc[di][1]*dn; o.z=acc[di][2]*dn; o.w=acc[di][3]*dn;
    *(float4*)&op[(d0+di)*16 + b0] = o;
  }
}

__global__ __launch_bounds__(256) void k_gemm2(const float* __restrict__ h1, const float* __restrict__ W2,
                                               const float* __restrict__ dinv, float* __restrict__ ht){
  __shared__ float W2s[DDF*DDF];        // 16 KB
  __shared__ float hs[4*1024];          // 16 KB, layout [node][k][b] (direct copy)
  int t = threadIdx.x;
  int node0 = blockIdx.x*4;
  for (int i=t;i<DDF*DDF;i+=256) W2s[i] = W2[i];
  const float4* src = (const float4*)&h1[(size_t)node0*1024];
  float4* dst4 = (float4*)hs;
  for (int i=t;i<1024;i+=256) dst4[i] = src[i];
  __syncthreads();
  int ln = t>>6, l = t&63;
  int d0 = (l&15)*4, b0 = (l>>4)*4;
  float acc[4][4] = {};
  for (int k=0;k<DDF;k++){
    const float4 wv = *(const float4*)&W2s[k*DDF + d0];
    const float4 xv = *(const float4*)&hs[ln*1024 + k*16 + b0];
    float w[4]={wv.x,wv.y,wv.z,wv.w}, xr[4]={xv.x,xv.y,xv.z,xv.w};
    #pragma unroll
    for (int di=0;di<4;di++)
      #pragma unroll
      for (int bi=0;bi<4;bi++)
        acc[di][bi] = fmaf(w[di], xr[bi], acc[di][bi]);
  }
  int n = node0 + ln;
  float dn = dinv[n];
  float* op = &ht[(size_t)n*1024];
  #pragma unroll
  for (int di=0;di<4;di++){
    float4 o; o.x=acc[di][0]*dn; o.y=acc[di][1]*dn; o.z=acc[di][2]*dn; o.w=acc[di][3]*dn;
    *(float4*)&op[(d0+di)*16 + b0] = o;
  }
}

// ---------- aggregation: out[n] = tanh(dinv[n]*(ht[n] + sum ht[src]) + bias[d]) ----------
__global__ __launch_bounds__(256) void k_agg(const float* __restrict__ ht, const int* __restrict__ csr,
                                             const int* __restrict__ offs, const float* __restrict__ dinv,
                                             const float* __restrict__ bias, float* __restrict__ out){
  int n = blockIdx.x, t = threadIdx.x;
  __shared__ int es[256];
  int beg = offs[n], end = offs[n+1];
  const float4 self = *(const float4*)&ht[(size_t)n*1024 + t*4];
  float ax = self.x, ay = self.y, az = self.z, aw = self.w;
  for (int base=beg; base<end; base+=256){
    int cnt = min(256, end-base);
    __syncthreads();
    if (t < cnt) es[t] = csr[base+t];
    __syncthreads();
    for (int j=0;j<cnt;j++){
      const float4 v = *(const float4*)&ht[(size_t)es[j]*1024 + t*4];
      ax+=v.x; ay+=v.y; az+=v.z; aw+=v.w;
    }
  }
  float dn = dinv[n];
  float bb = bias[t>>2];     // inner = t*4 = d*16+b -> d = t>>2
  float4 o;
  o.x = tanhf(fmaf(dn, ax, bb));
  o.y = tanhf(fmaf(dn, ay, bb));
  o.z = tanhf(fmaf(dn, az, bb));
  o.w = tanhf(fmaf(dn, aw, bb));
  *(float4*)&out[(size_t)n*1024 + t*4] = o;
}

// ---------- fused MLP layer 1, barrier-free ----------
// C[16 b x 320 j] = obs_t[K x 16]^T @ [Wc1 | Wa1 | Wb1]. Each lane reads a unique
// coalesced W float4 (W streamed exactly once); obs rows read directly from global
// with identical addresses across the 16 jq lanes of a rowgroup -> HW broadcast,
// no LDS, no barriers in the K-loop. 16b x 4j register tile: 64 FMA / 16 B of W.
#define FMA4(a,s,w) { a.x=fmaf(s,w.x,a.x); a.y=fmaf(s,w.y,a.y); a.z=fmaf(s,w.z,a.z); a.w=fmaf(s,w.w,a.w); }
__global__ __launch_bounds__(256) void k_mlp1f(const float* __restrict__ Wc1,
    const float* __restrict__ Wa1, const float* __restrict__ Wb1,
    const float* __restrict__ obs, float* __restrict__ partial){
  int t = threadIdx.x;
  int tile = blockIdx.y;
  const float* W; int sj, jb, cb;
  if      (tile==0){ W=Wc1; sj=64;  jb=0;  cb=0;   }
  else if (tile==1){ W=Wa1; sj=128; jb=0;  cb=64;  }
  else if (tile==2){ W=Wa1; sj=128; jb=64; cb=128; }
  else if (tile==3){ W=Wb1; sj=128; jb=0;  cb=192; }
  else             { W=Wb1; sj=128; jb=64; cb=256; }
  int jq = t & 15, rg = t >> 4;                 // 16 rowgroups per block
  const float* Wp = W + jb + jq*4;
  int r0 = blockIdx.x*CHROWS + rg;

  float4 acc[16];
  #pragma unroll
  for (int b=0;b<16;b++) acc[b] = make_float4(0.f,0.f,0.f,0.f);

  #pragma unroll 2
  for (int it=0; it<ITERS; it++){
    int r = r0 + it*16;
    float4 w = *(const float4*)&Wp[(size_t)r*sj];
    const float4* ob = (const float4*)&obs[(size_t)r*16];
    float4 o0 = ob[0], o1 = ob[1], o2 = ob[2], o3 = ob[3];
    FMA4(acc[ 0], o0.x, w); FMA4(acc[ 1], o0.y, w); FMA4(acc[ 2], o0.z, w); FMA4(acc[ 3], o0.w, w);
    FMA4(acc[ 4], o1.x, w); FMA4(acc[ 5], o1.y, w); FMA4(acc[ 6], o1.z, w); FMA4(acc[ 7], o1.w, w);
    FMA4(acc[ 8], o2.x, w); FMA4(acc[ 9], o2.y, w); FMA4(acc[10], o2.z, w); FMA4(acc[11], o2.w, w);
    FMA4(acc[12], o3.x, w); FMA4(acc[13], o3.y, w); FMA4(acc[14], o3.z, w); FMA4(acc[15], o3.w, w);
  }

  // reduce the 4 rowgroups within each wave (lanes differ by 16, 32)
  #pragma unroll
  for (int b=0;b<16;b++){
    float4 a = acc[b];
    a.x += __shfl_xor(a.x,16); a.y += __shfl_xor(a.y,16); a.z += __shfl_xor(a.z,16); a.w += __shfl_xor(a.w,16);
    a.x += __shfl_xor(a.x,32); a.y += __shfl_xor(a.y,32); a.z += __shfl_xor(a.z,32); a.w += __shfl_xor(a.w,32);
    acc[b] = a;
  }
  __shared__ float smem[4*1088];                // stride 68 -> 2-way max (free)
  int wv = t>>6, lane = t&63;
  if (lane < 16){
    #pragma unroll
    for (int b=0;b<16;b++)
      *(float4*)&smem[wv*1088 + lane*68 + b*4] = acc[b];
  }
  __syncthreads();
  int b2 = t & 15, jq2 = t >> 4;
  float4 s = make_float4(0.f,0.f,0.f,0.f);
  #pragma unroll
  for (int w2=0;w2<4;w2++){
    float4 v = *(const float4*)&smem[w2*1088 + jq2*68 + b2*4];
    s.x+=v.x; s.y+=v.y; s.z+=v.z; s.w+=v.w;
  }
  float* dst = partial + (size_t)blockIdx.x*(BB*JALL) + b2*JALL + cb + jq2*4;
  *(float4*)dst = s;
}

// ---------- two-stage partial reduce + bias + tanh -> act1[b][320] ----------
__global__ void k_red1(const float* __restrict__ partial, float* __restrict__ partial2){
  int o = blockIdx.x*256 + threadIdx.x;   // 0..5119
  int y = blockIdx.y;                     // 0..7
  int base = y*(NCH/8);
  float s0=0.f,s1=0.f,s2=0.f,s3=0.f,s4=0.f;
  for (int i=0;i<NCH/8;i+=5){
    s0 += partial[(size_t)(base+i+0)*(BB*JALL) + o];
    s1 += partial[(size_t)(base+i+1)*(BB*JALL) + o];
    s2 += partial[(size_t)(base+i+2)*(BB*JALL) + o];
    s3 += partial[(size_t)(base+i+3)*(BB*JALL) + o];
    s4 += partial[(size_t)(base+i+4)*(BB*JALL) + o];
  }
  partial2[(size_t)y*(BB*JALL) + o] = ((s0+s1)+(s2+s3))+s4;
}

__global__ void k_red2(const float* __restrict__ partial2, const float* __restrict__ bc1,
                       const float* __restrict__ ba1, const float* __restrict__ bb1,
                       float* __restrict__ act1){
  int o = blockIdx.x*256 + threadIdx.x;   // 0..5119
  float s = 0.f;
  #pragma unroll
  for (int y=0;y<8;y++) s += partial2[(size_t)y*(BB*JALL) + o];
  int col = o % JALL;
  float bias = col < 64 ? bc1[col] : (col < 192 ? ba1[col-64] : bb1[col-192]);
  act1[o] = tanhf(s + bias);
}

// ---------- tails: critic full, actor hidden layer 2 ----------
__global__ __launch_bounds__(256) void k_tail(const float* __restrict__ act1,
    const float* __restrict__ Wc2, const float* __restrict__ bc2,
    const float* __restrict__ Wc3, const float* __restrict__ bc3,
    const float* __restrict__ Wa2, const float* __restrict__ ba2,
    const float* __restrict__ Wb2, const float* __restrict__ bb2,
    float* __restrict__ ah2, float* __restrict__ bh2, float* __restrict__ out){
  int t = threadIdx.x;
  if (blockIdx.x == 0){
    __shared__ float c1[16][64];
    __shared__ float c2[16][64];
    for (int i=t;i<16*64;i+=256) c1[i>>6][i&63] = act1[(i>>6)*JALL + (i&63)];
    __syncthreads();
    int j = t & 63, brow = t >> 6;
    for (int i=0;i<4;i++){
      int b = brow*4 + i;
      float s = bc2[j];
      for (int k=0;k<64;k++) s = fmaf(c1[b][k], Wc2[k*64+j], s);
      c2[b][j] = tanhf(s);
    }
    __syncthreads();
    if (t < 16){
      float s = bc3[0];
      for (int k=0;k<64;k++) s = fmaf(c2[t][k], Wc3[k], s);
      out[3*BB*NN + t] = s;   // value at offset 240000
    }
  } else {
    const float* Wx2 = (blockIdx.x==1) ? Wa2 : Wb2;
    const float* bx2 = (blockIdx.x==1) ? ba2 : bb2;
    float* ox       = (blockIdx.x==1) ? ah2 : bh2;
    int cOff        = (blockIdx.x==1) ? 64 : 192;
    __shared__ float s1[16][128];
    for (int i=t;i<16*128;i+=256) s1[i>>7][i&127] = act1[(i>>7)*JALL + cOff + (i&127)];
    __syncthreads();
    int j = t & 127, bh = t >> 7;
    for (int i=0;i<8;i++){
      int b = bh*8 + i;
      float s = bx2[j];
      for (int k=0;k<128;k++) s = fmaf(s1[b][k], Wx2[k*128+j], s);
      ox[b*128 + j] = tanhf(s);
    }
  }
}

// ---------- final: actor layer 3 + Beta statistics ----------
__global__ __launch_bounds__(256) void k_final(const float* __restrict__ ah2, const float* __restrict__ bh2,
    const float* __restrict__ Wa3, const float* __restrict__ ba3,
    const float* __restrict__ Wb3, const float* __restrict__ bb3,
    float* __restrict__ out){
  __shared__ float as[128], bs[128];
  int t = threadIdx.x, b = blockIdx.y;
  if (t < 128){ as[t] = ah2[b*128+t]; bs[t] = bh2[b*128+t]; }
  __syncthreads();
  int n = blockIdx.x*256 + t;
  if (n >= NN) return;
  float sa = ba3[n], sb = bb3[n];
  #pragma unroll 4
  for (int k=0;k<128;k++){
    sa = fmaf(as[k], Wa3[k*NN+n], sa);
    sb = fmaf(bs[k], Wb3[k*NN+n], sb);
  }
  float alpha = 1.f + softplusf_(sa);
  float beta  = 1.f + softplusf_(sb);
  float action = alpha/(alpha+beta);
  float la = logf(action), lb = log1pf(-action);
  float logBt = gammalnf_(alpha) + gammalnf_(beta) - gammalnf_(alpha+beta);
  float logp = (alpha-1.f)*la + (beta-1.f)*lb - logBt;
  float ent = logBt - (alpha-1.f)*digammaf_(alpha) - (beta-1.f)*digammaf_(beta)
            + (alpha+beta-2.f)*digammaf_(alpha+beta);
  int o = b*NN + n;
  out[o]               = action;
  out[BB*NN + o]       = logp;
  out[2*BB*NN + o]     = ent;
}

extern "C" void kernel_launch(void* const* d_in, const int* in_sizes, int n_in,
                              void* d_out, int out_size, void* d_ws, size_t ws_size,
                              hipStream_t stream)
{
  const float* x   = (const float*)d_in[0];
  const int*   ei  = (const int*)d_in[1];
  const float* W1  = (const float*)d_in[2];
  const float* b1  = (const float*)d_in[3];
  const float* W2  = (const float*)d_in[4];
  const float* b2  = (const float*)d_in[5];
  const float* Wc1 = (const float*)d_in[6];
  const float* bc1 = (const float*)d_in[7];
  const float* Wc2 = (const float*)d_in[8];
  const float* bc2 = (const float*)d_in[9];
  const float* Wc3 = (const float*)d_in[10];
  const float* bc3 = (const float*)d_in[11];
  const float* Wa1 = (const float*)d_in[12];
  const float* ba1 = (const float*)d_in[13];
  const float* Wa2 = (const float*)d_in[14];
  const float* ba2 = (const float*)d_in[15];
  const float* Wa3 = (const float*)d_in[16];
  const float* ba3 = (const float*)d_in[17];
  const float* Wb1 = (const float*)d_in[18];
  const float* bb1 = (const float*)d_in[19];
  const float* Wb2 = (const float*)d_in[20];
  const float* bb2 = (const float*)d_in[21];
  const float* Wb3 = (const float*)d_in[22];
  const float* bb3 = (const float*)d_in[23];
  float* out = (float*)d_out;
  const int E = in_sizes[1]/2;

  char* p = (char*)d_ws;
  auto carve = [&](size_t bytes)->char*{ char* r = p; p += (bytes + 255) & ~(size_t)255; return r; };
  int*   deg      = (int*)carve((size_t)NN*4);
  int*   offs     = (int*)carve((size_t)(NN+1)*4);
  int*   cursor   = (int*)carve((size_t)NN*4);
  float* dinv     = (float*)carve((size_t)NN*4);
  int*   csr      = (int*)carve((size_t)E*4);
  float* partial2 = (float*)carve((size_t)8*BB*JALL*4);
  float* act1     = (float*)carve((size_t)BB*JALL*4);
  float* ah2      = (float*)carve((size_t)BB*128*4);
  float* bh2      = (float*)carve((size_t)BB*128*4);
  float* bufA     = (float*)carve((size_t)NN*1024*4);   // ht (pre-agg); later overlaid by partial
  float* bufB     = (float*)carve((size_t)NN*1024*4);   // h1, then obs_t
  float* partial  = bufA;   // NCH*BB*JALL*4 = 20,480,000 B == bufA size; bufA dead after 2nd k_agg

  hipMemsetAsync(deg, 0, (size_t)NN*4, stream);
  k_count<<<(E+255)/256, 256, 0, stream>>>(ei, deg, E);
  k_scan<<<1, 1024, 0, stream>>>(deg, offs, cursor, dinv);
  k_fill<<<(E+255)/256, 256, 0, stream>>>(ei, cursor, csr, E);

  k_gemm1<<<NN/4, 256, 0, stream>>>(x, W1, dinv, bufA);
  k_agg<<<NN, 256, 0, stream>>>(bufA, csr, offs, dinv, b1, bufB);
  k_gemm2<<<NN/4, 256, 0, stream>>>(bufB, W2, dinv, bufA);
  k_agg<<<NN, 256, 0, stream>>>(bufA, csr, offs, dinv, b2, bufB);   // bufB = obs_t[r][b]

  k_mlp1f<<<dim3(NCH, 5), 256, 0, stream>>>(Wc1, Wa1, Wb1, bufB, partial);
  k_red1<<<dim3((BB*JALL)/256, 8), 256, 0, stream>>>(partial, partial2);
  k_red2<<<(BB*JALL)/256, 256, 0, stream>>>(partial2, bc1, ba1, bb1, act1);

  k_tail<<<3, 256, 0, stream>>>(act1, Wc2, bc2, Wc3, bc3, Wa2, ba2, Wb2, bb2, ah2, bh2, out);
  k_final<<<dim3(20, BB), 256, 0, stream>>>(ah2, bh2, Wa3, ba3, Wb3, bb3, out);
}